// Round 18
// baseline (160.809 us; speedup 1.0000x reference)
//
#include <hip/hip_runtime.h>
#include <hip/hip_bf16.h>
#include <cstdint>
#include <cstddef>

typedef __attribute__((ext_vector_type(8))) short bf16x8;    // 8 bf16 in 4 VGPRs
typedef __attribute__((ext_vector_type(4))) float f32x4;
typedef __attribute__((ext_vector_type(16))) float f32x16;

// Native bf16 convert (RNE).
static __device__ __forceinline__ unsigned short f2bf(float f) {
    __hip_bfloat16 h = __float2bfloat16(f);
    return *reinterpret_cast<unsigned short*>(&h);
}
static __device__ __forceinline__ float bf2f(unsigned short u) {
    union { unsigned int i; float f; } x; x.i = ((unsigned int)u) << 16;
    return x.f;
}

static __device__ __forceinline__ f32x4 mfma_bf16(bf16x8 a, bf16x8 b, f32x4 c) {
    return __builtin_amdgcn_mfma_f32_16x16x32_bf16(a, b, c, 0, 0, 0);
}
static __device__ __forceinline__ f32x16 mfma32(bf16x8 a, bf16x8 b, f32x16 c) {
    return __builtin_amdgcn_mfma_f32_32x32x16_bf16(a, b, c, 0, 0, 0);
}

static __device__ __forceinline__ bf16x8 pack8(float4 a, float4 b) {
    bf16x8 f;
    f[0]=(short)f2bf(a.x); f[1]=(short)f2bf(a.y); f[2]=(short)f2bf(a.z); f[3]=(short)f2bf(a.w);
    f[4]=(short)f2bf(b.x); f[5]=(short)f2bf(b.y); f[6]=(short)f2bf(b.z); f[7]=(short)f2bf(b.w);
    return f;
}

// Branchless GELU via Hastings 3-term erf (|erf err| < 2.5e-5).
static __device__ __forceinline__ float gelu_erf(float v) {
    float s = v * 0.70710678118654752f;
    float a = fabsf(s);
    float t = __builtin_amdgcn_rcpf(1.0f + 0.47047f * a);
    float poly = ((0.7478556f * t - 0.0958798f) * t + 0.3480242f) * t;
    float e = 1.0f - poly * __expf(-a * a);
    float erfv = copysignf(e, s);
    return 0.5f * v * (1.0f + erfv);
}

// async 16B global -> LDS (linear dest: wave-uniform base + lane*16)
static __device__ __forceinline__ void load_lds16(const unsigned short* g, unsigned short* l) {
    __builtin_amdgcn_global_load_lds(
        (const __attribute__((address_space(1))) unsigned int*)g,
        (__attribute__((address_space(3))) unsigned int*)l, 16, 0, 0);
}

// ---------------------------------------------------------------------------
// Attention: one block per (window, head). Writes bf16 (to ws) or fp32 (d_out).
// ---------------------------------------------------------------------------
template <bool BF16X>
__global__ __launch_bounds__(256) void attn_kernel(
    const float* __restrict__ q, const float* __restrict__ k,
    const float* __restrict__ v, const float* __restrict__ mask,
    float* __restrict__ xo_f, unsigned short* __restrict__ xo_b)
{
    __shared__ unsigned short Qs[64][40];
    __shared__ unsigned short Ks[64][40];
    __shared__ unsigned short Vt[32][72];
    __shared__ unsigned short Ps[64][72];

    const int tid  = threadIdx.x;
    const int b    = blockIdx.x >> 3;
    const int h    = blockIdx.x & 7;
    const int lane = tid & 63;
    const int l15  = lane & 15;
    const int g    = lane >> 4;
    const int w    = tid >> 6;

    {
        int row = tid >> 2;
        int seg = tid & 3;
        size_t base = ((size_t)(b * 64 + row)) * 256 + h * 32 + seg * 8;

        float4 a0 = *(const float4*)(q + base);
        float4 a1 = *(const float4*)(q + base + 4);
        unsigned short* p = &Qs[row][seg * 8];
        p[0]=f2bf(a0.x); p[1]=f2bf(a0.y); p[2]=f2bf(a0.z); p[3]=f2bf(a0.w);
        p[4]=f2bf(a1.x); p[5]=f2bf(a1.y); p[6]=f2bf(a1.z); p[7]=f2bf(a1.w);

        a0 = *(const float4*)(k + base);
        a1 = *(const float4*)(k + base + 4);
        p = &Ks[row][seg * 8];
        p[0]=f2bf(a0.x); p[1]=f2bf(a0.y); p[2]=f2bf(a0.z); p[3]=f2bf(a0.w);
        p[4]=f2bf(a1.x); p[5]=f2bf(a1.y); p[6]=f2bf(a1.z); p[7]=f2bf(a1.w);

        a0 = *(const float4*)(v + base);
        a1 = *(const float4*)(v + base + 4);
        int c = seg * 8;
        Vt[c + 0][row] = f2bf(a0.x);
        Vt[c + 1][row] = f2bf(a0.y);
        Vt[c + 2][row] = f2bf(a0.z);
        Vt[c + 3][row] = f2bf(a0.w);
        Vt[c + 4][row] = f2bf(a1.x);
        Vt[c + 5][row] = f2bf(a1.y);
        Vt[c + 6][row] = f2bf(a1.z);
        Vt[c + 7][row] = f2bf(a1.w);
    }
    __syncthreads();

    f32x4 s[4];
    {
        bf16x8 aQ = *(const bf16x8*)&Qs[w * 16 + l15][g * 8];
        #pragma unroll
        for (int ct = 0; ct < 4; ++ct) {
            bf16x8 bK = *(const bf16x8*)&Ks[ct * 16 + l15][g * 8];
            f32x4 z = {0.f, 0.f, 0.f, 0.f};
            s[ct] = mfma_bf16(aQ, bK, z);
        }
    }

    const float* mbase = mask + (size_t)(b & 63) * 4096;
    const float INV = 0.17677669529663688f;
    float rsum[4];
    #pragma unroll
    for (int r = 0; r < 4; ++r) {
        int row = w * 16 + g * 4 + r;
        float pr[4];
        #pragma unroll
        for (int ct = 0; ct < 4; ++ct)
            pr[ct] = (s[ct][r] + mbase[row * 64 + ct * 16 + l15]) * INV;
        float m = fmaxf(fmaxf(pr[0], pr[1]), fmaxf(pr[2], pr[3]));
        #pragma unroll
        for (int off = 1; off < 16; off <<= 1)
            m = fmaxf(m, __shfl_xor(m, off));
        float sum = 0.f;
        #pragma unroll
        for (int ct = 0; ct < 4; ++ct) { pr[ct] = __expf(pr[ct] - m); sum += pr[ct]; }
        #pragma unroll
        for (int off = 1; off < 16; off <<= 1)
            sum += __shfl_xor(sum, off);
        rsum[r] = sum;
        #pragma unroll
        for (int ct = 0; ct < 4; ++ct)
            Ps[row][ct * 16 + l15] = f2bf(pr[ct]);
    }

    f32x4 o[2] = {};
    #pragma unroll
    for (int ks = 0; ks < 2; ++ks) {
        bf16x8 pa = *(const bf16x8*)&Ps[w * 16 + l15][ks * 32 + g * 8];
        #pragma unroll
        for (int n = 0; n < 2; ++n) {
            bf16x8 vb = *(const bf16x8*)&Vt[n * 16 + l15][ks * 32 + g * 8];
            o[n] = mfma_bf16(pa, vb, o[n]);
        }
    }

    #pragma unroll
    for (int n = 0; n < 2; ++n) {
        #pragma unroll
        for (int r = 0; r < 4; ++r) {
            int row = w * 16 + g * 4 + r;
            size_t idx = ((size_t)(b * 64 + row)) * 256 + h * 32 + n * 16 + l15;
            float val = o[n][r] / rsum[r];
            if (BF16X) xo_b[idx] = f2bf(val);
            else       xo_f[idx] = val;
        }
    }
}

// ---------------------------------------------------------------------------
// sigma(a): hidden value placed at 32x32-MFMA A-row position a so that the
// h-MFMA acc regs deliver hidden = (r>>3)*16 + hi*8 + (r&7).
// ---------------------------------------------------------------------------
static __device__ __forceinline__ int sigma32(int a) {
    return ((a >> 4) & 1) * 16 + ((a >> 2) & 1) * 8 + ((a >> 3) & 1) * 4 + (a & 3);
}

// prep_w1: chunk c, 16 spans ks of 512 shorts (unchanged, proven).
__global__ __launch_bounds__(256) void prep_w1(const float* __restrict__ src,
                                               unsigned short* __restrict__ dst)
{
    const int c = blockIdx.x;
    const int t = threadIdx.x;
    #pragma unroll
    for (int i = 0; i < 4; ++i) {
        int idx = i * 256 + t;              // 0..1023
        int ks  = idx >> 6;
        int l   = idx & 63;
        int l31 = l & 31, hi = l >> 5;
        int n   = c * 32 + sigma32(l31);
        unsigned short tmp[8];
        #pragma unroll
        for (int e = 0; e < 8; ++e)
            tmp[e] = f2bf(src[(size_t)(ks * 16 + hi * 8 + e) * 1024 + n]);
        *(bf16x8*)(dst + (size_t)c * 8192 + ks * 512 + l * 8) = *(const bf16x8*)tmp;
    }
}

// prep_w2 (unchanged, proven)
__global__ __launch_bounds__(256) void prep_w2(const float* __restrict__ src,
                                               unsigned short* __restrict__ dst)
{
    const int c = blockIdx.x;
    const int t = threadIdx.x;
    #pragma unroll
    for (int i = 0; i < 4; ++i) {
        int idx  = i * 256 + t;
        int span = idx >> 6;                // 0..15
        int l    = idx & 63;
        int n    = span >> 1;
        int j    = span & 1;
        int l31  = l & 31, hi = l >> 5;
        unsigned short tmp[8];
        #pragma unroll
        for (int e = 0; e < 8; ++e)
            tmp[e] = f2bf(src[(size_t)(c * 32 + j * 16 + hi * 8 + e) * 256 + n * 32 + l31]);
        *(bf16x8*)(dst + (size_t)c * 8192 + span * 512 + l * 8) = *(const bf16x8*)tmp;
    }
}

// ---------------------------------------------------------------------------
// Fused MLP v17 = v16 + dependency-chain shortening:
//   (1) hacc split into two 8-long MFMA chains (K halves), merged at GELU;
//   (2) GELU/out split in halves: aH0's 8 out-MFMAs issue while aH1's GELU
//       runs on the VALU pipe.
// ---------------------------------------------------------------------------
template <bool BF16X>
__global__ __launch_bounds__(256, 2) void mlp_fused(
    const float* __restrict__ xin_f, const unsigned short* __restrict__ xin_b,
    float* __restrict__ out,
    const unsigned short* __restrict__ wt1, const float* __restrict__ b1,
    const unsigned short* __restrict__ wt2, const float* __restrict__ b2)
{
    __shared__ unsigned short w1c[2][8192];     // 16 KB per buf
    __shared__ unsigned short w2c[2][8192];
    __shared__ float b1s[1024];

    const int tid  = threadIdx.x;
    const int lane = tid & 63;
    const int l31  = lane & 31;
    const int hi   = lane >> 5;
    const int wid  = tid >> 6;                  // 0..3
    const int fb   = lane * 8;                  // frag offset within 512-short span

    const size_t rowbase = (size_t)blockIdx.x * 128 + wid * 32;

    auto stage = [&](const unsigned short* gbase, unsigned short* lbase) {
        #pragma unroll
        for (int i = 0; i < 4; ++i) {
            load_lds16(gbase + (i * 256 + tid) * 8,
                       lbase + (i * 256 + wid * 64) * 8);
        }
    };

    stage(wt1, &w1c[0][0]);
    stage(wt2, &w2c[0][0]);

    b1s[tid]       = b1[tid];
    b1s[tid + 256] = b1[tid + 256];
    b1s[tid + 512] = b1[tid + 512];
    b1s[tid + 768] = b1[tid + 768];

    // x fragments: B-operand, lane = own x-row (l31), k = hi*8+e. 64 VGPR.
    bf16x8 xf[16];
    if (BF16X) {
        const unsigned short* xr = xin_b + (rowbase + l31) * 256;
        #pragma unroll
        for (int ks = 0; ks < 16; ++ks)
            xf[ks] = *(const bf16x8*)(xr + ks * 16 + hi * 8);
    } else {
        const float* xr = xin_f + (rowbase + l31) * 256;
        #pragma unroll
        for (int ks = 0; ks < 16; ++ks) {
            float4 a0 = *(const float4*)(xr + ks * 16 + hi * 8);
            float4 a1 = *(const float4*)(xr + ks * 16 + hi * 8 + 4);
            xf[ks] = pack8(a0, a1);
        }
    }

    f32x16 oacc[8] = {};   // 32 rows x 256 cols (8 col-tiles of 32)

    for (int c = 0; c < 32; ++c) {
        const int cur = c & 1;
        __syncthreads();   // drains chunk-c DMA; frees buf cur^1 for prefetch

        if (c < 31) {
            stage(wt1 + (size_t)(c + 1) * 8192, &w1c[cur ^ 1][0]);
            stage(wt2 + (size_t)(c + 1) * 8192, &w2c[cur ^ 1][0]);
        }

        // ---- bias-seeded h accumulator (chain A) + zero chain B ----
        f32x16 haccA;
        {
            const float* bp = &b1s[c * 32 + hi * 8];
            float4 b0 = *(const float4*)(bp);
            float4 b1v = *(const float4*)(bp + 4);
            float4 b2v = *(const float4*)(bp + 16);
            float4 b3 = *(const float4*)(bp + 20);
            haccA[0]=b0.x;  haccA[1]=b0.y;  haccA[2]=b0.z;  haccA[3]=b0.w;
            haccA[4]=b1v.x; haccA[5]=b1v.y; haccA[6]=b1v.z; haccA[7]=b1v.w;
            haccA[8]=b2v.x; haccA[9]=b2v.y; haccA[10]=b2v.z; haccA[11]=b2v.w;
            haccA[12]=b3.x; haccA[13]=b3.y; haccA[14]=b3.z; haccA[15]=b3.w;
        }
        f32x16 haccB = {};

        // ---- h-phase: two independent 8-long MFMA chains over K halves ----
        __builtin_amdgcn_s_setprio(1);
        #pragma unroll
        for (int ks = 0; ks < 8; ++ks) {
            bf16x8 wfA = *(const bf16x8*)&w1c[cur][ks * 512 + fb];
            bf16x8 wfB = *(const bf16x8*)&w1c[cur][(8 + ks) * 512 + fb];
            haccA = mfma32(wfA, xf[ks], haccA);
            haccB = mfma32(wfB, xf[8 + ks], haccB);
        }
        __builtin_amdgcn_s_setprio(0);

        // ---- GELU half 0 -> aH0; its out-MFMAs issue while half 1's GELU
        //      runs on the VALU pipe ----
        bf16x8 aH0;
        #pragma unroll
        for (int e = 0; e < 8; ++e)
            aH0[e] = (short)f2bf(gelu_erf(haccA[e] + haccB[e]));

        __builtin_amdgcn_s_setprio(1);
        #pragma unroll
        for (int n = 0; n < 8; ++n) {
            bf16x8 bF0 = *(const bf16x8*)&w2c[cur][(n * 2 + 0) * 512 + fb];
            oacc[n] = mfma32(aH0, bF0, oacc[n]);
        }
        __builtin_amdgcn_s_setprio(0);

        bf16x8 aH1;
        #pragma unroll
        for (int e = 0; e < 8; ++e)
            aH1[e] = (short)f2bf(gelu_erf(haccA[e + 8] + haccB[e + 8]));

        __builtin_amdgcn_s_setprio(1);
        #pragma unroll
        for (int n = 0; n < 8; ++n) {
            bf16x8 bF1 = *(const bf16x8*)&w2c[cur][(n * 2 + 1) * 512 + fb];
            oacc[n] = mfma32(aH1, bF1, oacc[n]);
        }
        __builtin_amdgcn_s_setprio(0);
    }

    // ---- epilogue: out = oacc + b2 + residual ----
    // reg r -> row_local = (r&3) + 8*(r>>2) + 4*hi; col = n*32 + l31.
    #pragma unroll
    for (int n = 0; n < 8; ++n) {
        int col = n * 32 + l31;
        float bias = b2[col];
        #pragma unroll
        for (int r = 0; r < 16; ++r) {
            int row_local = (r & 3) + 8 * (r >> 2) + 4 * hi;
            size_t idx = (rowbase + row_local) * 256 + col;
            float resid = BF16X ? bf2f(xin_b[idx]) : xin_f[idx];
            out[idx] = oacc[n][r] + bias + resid;
        }
    }
}

// ---------------------------------------------------------------------------
extern "C" void kernel_launch(void* const* d_in, const int* in_sizes, int n_in,
                              void* d_out, int out_size, void* d_ws, size_t ws_size,
                              hipStream_t stream)
{
    const float* q    = (const float*)d_in[0];
    const float* k    = (const float*)d_in[1];
    const float* v    = (const float*)d_in[2];
    const float* mask = (const float*)d_in[3];
    const float* w1   = (const float*)d_in[6];
    const float* b1   = (const float*)d_in[7];
    const float* w2   = (const float*)d_in[8];
    const float* b2   = (const float*)d_in[9];

    float* out = (float*)d_out;

    unsigned short* wt1 = (unsigned short*)d_ws;                 // 512 KB
    unsigned short* wt2 = wt1 + (size_t)1024 * 256;              // 512 KB
    unsigned short* xbf = wt2 + (size_t)1024 * 256;              // 32 MB (bf16 x)

    const size_t need = (size_t)2 * 1024 * 256 * 2 + (size_t)65536 * 256 * 2;

    prep_w1<<<32, 256, 0, stream>>>(w1, wt1);
    prep_w2<<<32, 256, 0, stream>>>(w2, wt2);

    if (ws_size >= need) {
        attn_kernel<true><<<8192, 256, 0, stream>>>(q, k, v, mask, nullptr, xbf);
        mlp_fused<true><<<512, 256, 0, stream>>>(nullptr, xbf, out, wt1, b1, wt2, b2);
    } else {
        attn_kernel<false><<<8192, 256, 0, stream>>>(q, k, v, mask, out, nullptr);
        mlp_fused<false><<<512, 256, 0, stream>>>(out, nullptr, out, wt1, b1, wt2, b2);
    }
}

// Round 19
// 153.023 us; speedup vs baseline: 1.0509x; 1.0509x over previous
//
#include <hip/hip_runtime.h>
#include <hip/hip_bf16.h>
#include <cstdint>
#include <cstddef>

typedef __attribute__((ext_vector_type(8))) short bf16x8;    // 8 bf16 in 4 VGPRs
typedef __attribute__((ext_vector_type(4))) float f32x4;
typedef __attribute__((ext_vector_type(16))) float f32x16;

// Native bf16 convert (RNE).
static __device__ __forceinline__ unsigned short f2bf(float f) {
    __hip_bfloat16 h = __float2bfloat16(f);
    return *reinterpret_cast<unsigned short*>(&h);
}
static __device__ __forceinline__ float bf2f(unsigned short u) {
    union { unsigned int i; float f; } x; x.i = ((unsigned int)u) << 16;
    return x.f;
}

static __device__ __forceinline__ f32x4 mfma_bf16(bf16x8 a, bf16x8 b, f32x4 c) {
    return __builtin_amdgcn_mfma_f32_16x16x32_bf16(a, b, c, 0, 0, 0);
}
static __device__ __forceinline__ f32x16 mfma32(bf16x8 a, bf16x8 b, f32x16 c) {
    return __builtin_amdgcn_mfma_f32_32x32x16_bf16(a, b, c, 0, 0, 0);
}

static __device__ __forceinline__ bf16x8 pack8(float4 a, float4 b) {
    bf16x8 f;
    f[0]=(short)f2bf(a.x); f[1]=(short)f2bf(a.y); f[2]=(short)f2bf(a.z); f[3]=(short)f2bf(a.w);
    f[4]=(short)f2bf(b.x); f[5]=(short)f2bf(b.y); f[6]=(short)f2bf(b.z); f[7]=(short)f2bf(b.w);
    return f;
}

// Branchless GELU via Hastings 3-term erf (|erf err| < 2.5e-5).
static __device__ __forceinline__ float gelu_erf(float v) {
    float s = v * 0.70710678118654752f;
    float a = fabsf(s);
    float t = __builtin_amdgcn_rcpf(1.0f + 0.47047f * a);
    float poly = ((0.7478556f * t - 0.0958798f) * t + 0.3480242f) * t;
    float e = 1.0f - poly * __expf(-a * a);
    float erfv = copysignf(e, s);
    return 0.5f * v * (1.0f + erfv);
}

// async 16B global -> LDS (linear dest: wave-uniform base + lane*16)
static __device__ __forceinline__ void load_lds16(const unsigned short* g, unsigned short* l) {
    __builtin_amdgcn_global_load_lds(
        (const __attribute__((address_space(1))) unsigned int*)g,
        (__attribute__((address_space(3))) unsigned int*)l, 16, 0, 0);
}

// sigma(a): hidden value placed at 32x32-MFMA A-row position a so that the
// h-MFMA acc regs deliver hidden = (r>>3)*16 + hi*8 + (r&7).
static __device__ __forceinline__ int sigma32(int a) {
    return ((a >> 4) & 1) * 16 + ((a >> 2) & 1) * 8 + ((a >> 3) & 1) * 4 + (a & 3);
}

// ---------------------------------------------------------------------------
// Merged attention + weight-prep kernel. Blocks 0..8191: attention for
// (window, head). Blocks 8192..8223: prep_w1 chunk (bid-8192). Blocks
// 8224..8255: prep_w2 chunk (bid-8224). Prep blocks touch no LDS.
// ---------------------------------------------------------------------------
template <bool BF16X>
__global__ __launch_bounds__(256) void attn_prep_kernel(
    const float* __restrict__ q, const float* __restrict__ k,
    const float* __restrict__ v, const float* __restrict__ mask,
    float* __restrict__ xo_f, unsigned short* __restrict__ xo_b,
    const float* __restrict__ w1, unsigned short* __restrict__ wt1,
    const float* __restrict__ w2, unsigned short* __restrict__ wt2)
{
    const int tid = threadIdx.x;

    if (blockIdx.x >= 8192) {
        int pb = blockIdx.x - 8192;
        if (pb < 32) {
            // ---- prep_w1 chunk pb ----
            const int c = pb;
            #pragma unroll
            for (int i = 0; i < 4; ++i) {
                int idx = i * 256 + tid;            // 0..1023
                int ks  = idx >> 6;
                int l   = idx & 63;
                int l31 = l & 31, hi = l >> 5;
                int n   = c * 32 + sigma32(l31);
                unsigned short tmp[8];
                #pragma unroll
                for (int e = 0; e < 8; ++e)
                    tmp[e] = f2bf(w1[(size_t)(ks * 16 + hi * 8 + e) * 1024 + n]);
                *(bf16x8*)(wt1 + (size_t)c * 8192 + ks * 512 + l * 8) = *(const bf16x8*)tmp;
            }
        } else {
            // ---- prep_w2 chunk pb-32 ----
            const int c = pb - 32;
            #pragma unroll
            for (int i = 0; i < 4; ++i) {
                int idx  = i * 256 + tid;
                int span = idx >> 6;                // 0..15
                int l    = idx & 63;
                int n    = span >> 1;
                int j    = span & 1;
                int l31  = l & 31, hi = l >> 5;
                unsigned short tmp[8];
                #pragma unroll
                for (int e = 0; e < 8; ++e)
                    tmp[e] = f2bf(w2[(size_t)(c * 32 + j * 16 + hi * 8 + e) * 256 + n * 32 + l31]);
                *(bf16x8*)(wt2 + (size_t)c * 8192 + span * 512 + l * 8) = *(const bf16x8*)tmp;
            }
        }
        return;
    }

    // ---- attention ----
    __shared__ unsigned short Qs[64][40];
    __shared__ unsigned short Ks[64][40];
    __shared__ unsigned short Vt[32][72];
    __shared__ unsigned short Ps[64][72];

    const int b    = blockIdx.x >> 3;
    const int h    = blockIdx.x & 7;
    const int lane = tid & 63;
    const int l15  = lane & 15;
    const int g    = lane >> 4;
    const int w    = tid >> 6;

    {
        int row = tid >> 2;
        int seg = tid & 3;
        size_t base = ((size_t)(b * 64 + row)) * 256 + h * 32 + seg * 8;

        float4 a0 = *(const float4*)(q + base);
        float4 a1 = *(const float4*)(q + base + 4);
        unsigned short* p = &Qs[row][seg * 8];
        p[0]=f2bf(a0.x); p[1]=f2bf(a0.y); p[2]=f2bf(a0.z); p[3]=f2bf(a0.w);
        p[4]=f2bf(a1.x); p[5]=f2bf(a1.y); p[6]=f2bf(a1.z); p[7]=f2bf(a1.w);

        a0 = *(const float4*)(k + base);
        a1 = *(const float4*)(k + base + 4);
        p = &Ks[row][seg * 8];
        p[0]=f2bf(a0.x); p[1]=f2bf(a0.y); p[2]=f2bf(a0.z); p[3]=f2bf(a0.w);
        p[4]=f2bf(a1.x); p[5]=f2bf(a1.y); p[6]=f2bf(a1.z); p[7]=f2bf(a1.w);

        a0 = *(const float4*)(v + base);
        a1 = *(const float4*)(v + base + 4);
        int c = seg * 8;
        Vt[c + 0][row] = f2bf(a0.x);
        Vt[c + 1][row] = f2bf(a0.y);
        Vt[c + 2][row] = f2bf(a0.z);
        Vt[c + 3][row] = f2bf(a0.w);
        Vt[c + 4][row] = f2bf(a1.x);
        Vt[c + 5][row] = f2bf(a1.y);
        Vt[c + 6][row] = f2bf(a1.z);
        Vt[c + 7][row] = f2bf(a1.w);
    }
    __syncthreads();

    f32x4 s[4];
    {
        bf16x8 aQ = *(const bf16x8*)&Qs[w * 16 + l15][g * 8];
        #pragma unroll
        for (int ct = 0; ct < 4; ++ct) {
            bf16x8 bK = *(const bf16x8*)&Ks[ct * 16 + l15][g * 8];
            f32x4 z = {0.f, 0.f, 0.f, 0.f};
            s[ct] = mfma_bf16(aQ, bK, z);
        }
    }

    const float* mbase = mask + (size_t)(b & 63) * 4096;
    const float INV = 0.17677669529663688f;
    float rsum[4];
    #pragma unroll
    for (int r = 0; r < 4; ++r) {
        int row = w * 16 + g * 4 + r;
        float pr[4];
        #pragma unroll
        for (int ct = 0; ct < 4; ++ct)
            pr[ct] = (s[ct][r] + mbase[row * 64 + ct * 16 + l15]) * INV;
        float m = fmaxf(fmaxf(pr[0], pr[1]), fmaxf(pr[2], pr[3]));
        #pragma unroll
        for (int off = 1; off < 16; off <<= 1)
            m = fmaxf(m, __shfl_xor(m, off));
        float sum = 0.f;
        #pragma unroll
        for (int ct = 0; ct < 4; ++ct) { pr[ct] = __expf(pr[ct] - m); sum += pr[ct]; }
        #pragma unroll
        for (int off = 1; off < 16; off <<= 1)
            sum += __shfl_xor(sum, off);
        rsum[r] = sum;
        #pragma unroll
        for (int ct = 0; ct < 4; ++ct)
            Ps[row][ct * 16 + l15] = f2bf(pr[ct]);
    }

    f32x4 o[2] = {};
    #pragma unroll
    for (int ks = 0; ks < 2; ++ks) {
        bf16x8 pa = *(const bf16x8*)&Ps[w * 16 + l15][ks * 32 + g * 8];
        #pragma unroll
        for (int n = 0; n < 2; ++n) {
            bf16x8 vb = *(const bf16x8*)&Vt[n * 16 + l15][ks * 32 + g * 8];
            o[n] = mfma_bf16(pa, vb, o[n]);
        }
    }

    #pragma unroll
    for (int n = 0; n < 2; ++n) {
        #pragma unroll
        for (int r = 0; r < 4; ++r) {
            int row = w * 16 + g * 4 + r;
            size_t idx = ((size_t)(b * 64 + row)) * 256 + h * 32 + n * 16 + l15;
            float val = o[n][r] / rsum[r];
            if (BF16X) xo_b[idx] = f2bf(val);
            else       xo_f[idx] = val;
        }
    }
}

// ---------------------------------------------------------------------------
// Fused MLP (v16 body — measured best): 32x32x16 MFMA, 256 thr = 4 waves x
// 32 rows, grid 512 (2 blocks/CU). Bias-seeded hacc, Hastings GELU, setprio
// around MFMA clusters, bf16 x input.
// ---------------------------------------------------------------------------
template <bool BF16X>
__global__ __launch_bounds__(256, 2) void mlp_fused(
    const float* __restrict__ xin_f, const unsigned short* __restrict__ xin_b,
    float* __restrict__ out,
    const unsigned short* __restrict__ wt1, const float* __restrict__ b1,
    const unsigned short* __restrict__ wt2, const float* __restrict__ b2)
{
    __shared__ unsigned short w1c[2][8192];     // 16 KB per buf
    __shared__ unsigned short w2c[2][8192];
    __shared__ float b1s[1024];

    const int tid  = threadIdx.x;
    const int lane = tid & 63;
    const int l31  = lane & 31;
    const int hi   = lane >> 5;
    const int wid  = tid >> 6;                  // 0..3
    const int fb   = lane * 8;                  // frag offset within 512-short span

    const size_t rowbase = (size_t)blockIdx.x * 128 + wid * 32;

    auto stage = [&](const unsigned short* gbase, unsigned short* lbase) {
        #pragma unroll
        for (int i = 0; i < 4; ++i) {
            load_lds16(gbase + (i * 256 + tid) * 8,
                       lbase + (i * 256 + wid * 64) * 8);
        }
    };

    stage(wt1, &w1c[0][0]);
    stage(wt2, &w2c[0][0]);

    b1s[tid]       = b1[tid];
    b1s[tid + 256] = b1[tid + 256];
    b1s[tid + 512] = b1[tid + 512];
    b1s[tid + 768] = b1[tid + 768];

    // x fragments: B-operand, lane = own x-row (l31), k = hi*8+e. 64 VGPR.
    bf16x8 xf[16];
    if (BF16X) {
        const unsigned short* xr = xin_b + (rowbase + l31) * 256;
        #pragma unroll
        for (int ks = 0; ks < 16; ++ks)
            xf[ks] = *(const bf16x8*)(xr + ks * 16 + hi * 8);
    } else {
        const float* xr = xin_f + (rowbase + l31) * 256;
        #pragma unroll
        for (int ks = 0; ks < 16; ++ks) {
            float4 a0 = *(const float4*)(xr + ks * 16 + hi * 8);
            float4 a1 = *(const float4*)(xr + ks * 16 + hi * 8 + 4);
            xf[ks] = pack8(a0, a1);
        }
    }

    f32x16 oacc[8] = {};   // 32 rows x 256 cols (8 col-tiles of 32)

    for (int c = 0; c < 32; ++c) {
        const int cur = c & 1;
        __syncthreads();   // drains chunk-c DMA; frees buf cur^1 for prefetch

        if (c < 31) {
            stage(wt1 + (size_t)(c + 1) * 8192, &w1c[cur ^ 1][0]);
            stage(wt2 + (size_t)(c + 1) * 8192, &w2c[cur ^ 1][0]);
        }

        // ---- bias-seeded h accumulator ----
        f32x16 hacc;
        {
            const float* bp = &b1s[c * 32 + hi * 8];
            float4 b0 = *(const float4*)(bp);
            float4 b1v = *(const float4*)(bp + 4);
            float4 b2v = *(const float4*)(bp + 16);
            float4 b3 = *(const float4*)(bp + 20);
            hacc[0]=b0.x;  hacc[1]=b0.y;  hacc[2]=b0.z;  hacc[3]=b0.w;
            hacc[4]=b1v.x; hacc[5]=b1v.y; hacc[6]=b1v.z; hacc[7]=b1v.w;
            hacc[8]=b2v.x; hacc[9]=b2v.y; hacc[10]=b2v.z; hacc[11]=b2v.w;
            hacc[12]=b3.x; hacc[13]=b3.y; hacc[14]=b3.z; hacc[15]=b3.w;
        }

        // ---- h-phase: 16 chained mfma32 over K=256 ----
        __builtin_amdgcn_s_setprio(1);
        #pragma unroll
        for (int ks = 0; ks < 16; ++ks) {
            bf16x8 wf = *(const bf16x8*)&w1c[cur][ks * 512 + fb];
            hacc = mfma32(wf, xf[ks], hacc);
        }
        __builtin_amdgcn_s_setprio(0);

        // ---- GELU in registers -> two out-MFMA A-frags ----
        bf16x8 aH0, aH1;
        #pragma unroll
        for (int e = 0; e < 8; ++e) {
            aH0[e] = (short)f2bf(gelu_erf(hacc[e]));
            aH1[e] = (short)f2bf(gelu_erf(hacc[e + 8]));
        }

        // ---- out-phase: 8 col-tiles x 2 K-halves ----
        __builtin_amdgcn_s_setprio(1);
        #pragma unroll
        for (int n = 0; n < 8; ++n) {
            bf16x8 bF0 = *(const bf16x8*)&w2c[cur][(n * 2 + 0) * 512 + fb];
            bf16x8 bF1 = *(const bf16x8*)&w2c[cur][(n * 2 + 1) * 512 + fb];
            oacc[n] = mfma32(aH0, bF0, oacc[n]);
            oacc[n] = mfma32(aH1, bF1, oacc[n]);
        }
        __builtin_amdgcn_s_setprio(0);
    }

    // ---- epilogue: out = oacc + b2 + residual ----
    // reg r -> row_local = (r&3) + 8*(r>>2) + 4*hi; col = n*32 + l31.
    #pragma unroll
    for (int n = 0; n < 8; ++n) {
        int col = n * 32 + l31;
        float bias = b2[col];
        #pragma unroll
        for (int r = 0; r < 16; ++r) {
            int row_local = (r & 3) + 8 * (r >> 2) + 4 * hi;
            size_t idx = (rowbase + row_local) * 256 + col;
            float resid = BF16X ? bf2f(xin_b[idx]) : xin_f[idx];
            out[idx] = oacc[n][r] + bias + resid;
        }
    }
}

// ---------------------------------------------------------------------------
extern "C" void kernel_launch(void* const* d_in, const int* in_sizes, int n_in,
                              void* d_out, int out_size, void* d_ws, size_t ws_size,
                              hipStream_t stream)
{
    const float* q    = (const float*)d_in[0];
    const float* k    = (const float*)d_in[1];
    const float* v    = (const float*)d_in[2];
    const float* mask = (const float*)d_in[3];
    const float* w1   = (const float*)d_in[6];
    const float* b1   = (const float*)d_in[7];
    const float* w2   = (const float*)d_in[8];
    const float* b2   = (const float*)d_in[9];

    float* out = (float*)d_out;

    unsigned short* wt1 = (unsigned short*)d_ws;                 // 512 KB
    unsigned short* wt2 = wt1 + (size_t)1024 * 256;              // 512 KB
    unsigned short* xbf = wt2 + (size_t)1024 * 256;              // 32 MB (bf16 x)

    const size_t need = (size_t)2 * 1024 * 256 * 2 + (size_t)65536 * 256 * 2;

    if (ws_size >= need) {
        attn_prep_kernel<true><<<8256, 256, 0, stream>>>(
            q, k, v, mask, nullptr, xbf, w1, wt1, w2, wt2);
        mlp_fused<true><<<512, 256, 0, stream>>>(
            nullptr, xbf, out, wt1, b1, wt2, b2);
    } else {
        attn_prep_kernel<false><<<8256, 256, 0, stream>>>(
            q, k, v, mask, out, nullptr, w1, wt1, w2, wt2);
        mlp_fused<false><<<512, 256, 0, stream>>>(
            out, nullptr, out, wt1, b1, wt2, b2);
    }
}

// Round 20
// 151.087 us; speedup vs baseline: 1.0643x; 1.0128x over previous
//
#include <hip/hip_runtime.h>
#include <hip/hip_bf16.h>
#include <cstdint>
#include <cstddef>

typedef __attribute__((ext_vector_type(8))) short bf16x8;    // 8 bf16 in 4 VGPRs
typedef __attribute__((ext_vector_type(4))) float f32x4;
typedef __attribute__((ext_vector_type(16))) float f32x16;

// Native bf16 convert (RNE).
static __device__ __forceinline__ unsigned short f2bf(float f) {
    __hip_bfloat16 h = __float2bfloat16(f);
    return *reinterpret_cast<unsigned short*>(&h);
}
static __device__ __forceinline__ float bf2f(unsigned short u) {
    union { unsigned int i; float f; } x; x.i = ((unsigned int)u) << 16;
    return x.f;
}

static __device__ __forceinline__ f32x4 mfma_bf16(bf16x8 a, bf16x8 b, f32x4 c) {
    return __builtin_amdgcn_mfma_f32_16x16x32_bf16(a, b, c, 0, 0, 0);
}
static __device__ __forceinline__ f32x16 mfma32(bf16x8 a, bf16x8 b, f32x16 c) {
    return __builtin_amdgcn_mfma_f32_32x32x16_bf16(a, b, c, 0, 0, 0);
}

static __device__ __forceinline__ bf16x8 pack8(float4 a, float4 b) {
    bf16x8 f;
    f[0]=(short)f2bf(a.x); f[1]=(short)f2bf(a.y); f[2]=(short)f2bf(a.z); f[3]=(short)f2bf(a.w);
    f[4]=(short)f2bf(b.x); f[5]=(short)f2bf(b.y); f[6]=(short)f2bf(b.z); f[7]=(short)f2bf(b.w);
    return f;
}

// Branchless GELU via Hastings 3-term erf (|erf err| < 2.5e-5).
static __device__ __forceinline__ float gelu_erf(float v) {
    float s = v * 0.70710678118654752f;
    float a = fabsf(s);
    float t = __builtin_amdgcn_rcpf(1.0f + 0.47047f * a);
    float poly = ((0.7478556f * t - 0.0958798f) * t + 0.3480242f) * t;
    float e = 1.0f - poly * __expf(-a * a);
    float erfv = copysignf(e, s);
    return 0.5f * v * (1.0f + erfv);
}

// async 16B global -> LDS (linear dest: wave-uniform base + lane*16)
static __device__ __forceinline__ void load_lds16(const unsigned short* g, unsigned short* l) {
    __builtin_amdgcn_global_load_lds(
        (const __attribute__((address_space(1))) unsigned int*)g,
        (__attribute__((address_space(3))) unsigned int*)l, 16, 0, 0);
}

// sigma(a): hidden value placed at 32x32-MFMA A-row position a so that the
// h-MFMA acc regs deliver hidden = (r>>3)*16 + hi*8 + (r&7).
static __device__ __forceinline__ int sigma32(int a) {
    return ((a >> 4) & 1) * 16 + ((a >> 2) & 1) * 8 + ((a >> 3) & 1) * 4 + (a & 3);
}

// ---------------------------------------------------------------------------
// Merged attention + weight-prep kernel (proven r19). Blocks 0..8191: attn.
// Blocks 8192..8223: prep_w1 chunk. Blocks 8224..8255: prep_w2 chunk.
// ---------------------------------------------------------------------------
template <bool BF16X>
__global__ __launch_bounds__(256) void attn_prep_kernel(
    const float* __restrict__ q, const float* __restrict__ k,
    const float* __restrict__ v, const float* __restrict__ mask,
    float* __restrict__ xo_f, unsigned short* __restrict__ xo_b,
    const float* __restrict__ w1, unsigned short* __restrict__ wt1,
    const float* __restrict__ w2, unsigned short* __restrict__ wt2)
{
    const int tid = threadIdx.x;

    if (blockIdx.x >= 8192) {
        int pb = blockIdx.x - 8192;
        if (pb < 32) {
            const int c = pb;
            #pragma unroll
            for (int i = 0; i < 4; ++i) {
                int idx = i * 256 + tid;            // 0..1023
                int ks  = idx >> 6;
                int l   = idx & 63;
                int l31 = l & 31, hi = l >> 5;
                int n   = c * 32 + sigma32(l31);
                unsigned short tmp[8];
                #pragma unroll
                for (int e = 0; e < 8; ++e)
                    tmp[e] = f2bf(w1[(size_t)(ks * 16 + hi * 8 + e) * 1024 + n]);
                *(bf16x8*)(wt1 + (size_t)c * 8192 + ks * 512 + l * 8) = *(const bf16x8*)tmp;
            }
        } else {
            const int c = pb - 32;
            #pragma unroll
            for (int i = 0; i < 4; ++i) {
                int idx  = i * 256 + tid;
                int span = idx >> 6;                // 0..15
                int l    = idx & 63;
                int n    = span >> 1;
                int j    = span & 1;
                int l31  = l & 31, hi = l >> 5;
                unsigned short tmp[8];
                #pragma unroll
                for (int e = 0; e < 8; ++e)
                    tmp[e] = f2bf(w2[(size_t)(c * 32 + j * 16 + hi * 8 + e) * 256 + n * 32 + l31]);
                *(bf16x8*)(wt2 + (size_t)c * 8192 + span * 512 + l * 8) = *(const bf16x8*)tmp;
            }
        }
        return;
    }

    // ---- attention ----
    __shared__ unsigned short Qs[64][40];
    __shared__ unsigned short Ks[64][40];
    __shared__ unsigned short Vt[32][72];
    __shared__ unsigned short Ps[64][72];

    const int b    = blockIdx.x >> 3;
    const int h    = blockIdx.x & 7;
    const int lane = tid & 63;
    const int l15  = lane & 15;
    const int g    = lane >> 4;
    const int w    = tid >> 6;

    {
        int row = tid >> 2;
        int seg = tid & 3;
        size_t base = ((size_t)(b * 64 + row)) * 256 + h * 32 + seg * 8;

        float4 a0 = *(const float4*)(q + base);
        float4 a1 = *(const float4*)(q + base + 4);
        unsigned short* p = &Qs[row][seg * 8];
        p[0]=f2bf(a0.x); p[1]=f2bf(a0.y); p[2]=f2bf(a0.z); p[3]=f2bf(a0.w);
        p[4]=f2bf(a1.x); p[5]=f2bf(a1.y); p[6]=f2bf(a1.z); p[7]=f2bf(a1.w);

        a0 = *(const float4*)(k + base);
        a1 = *(const float4*)(k + base + 4);
        p = &Ks[row][seg * 8];
        p[0]=f2bf(a0.x); p[1]=f2bf(a0.y); p[2]=f2bf(a0.z); p[3]=f2bf(a0.w);
        p[4]=f2bf(a1.x); p[5]=f2bf(a1.y); p[6]=f2bf(a1.z); p[7]=f2bf(a1.w);

        a0 = *(const float4*)(v + base);
        a1 = *(const float4*)(v + base + 4);
        int c = seg * 8;
        Vt[c + 0][row] = f2bf(a0.x);
        Vt[c + 1][row] = f2bf(a0.y);
        Vt[c + 2][row] = f2bf(a0.z);
        Vt[c + 3][row] = f2bf(a0.w);
        Vt[c + 4][row] = f2bf(a1.x);
        Vt[c + 5][row] = f2bf(a1.y);
        Vt[c + 6][row] = f2bf(a1.z);
        Vt[c + 7][row] = f2bf(a1.w);
    }
    __syncthreads();

    f32x4 s[4];
    {
        bf16x8 aQ = *(const bf16x8*)&Qs[w * 16 + l15][g * 8];
        #pragma unroll
        for (int ct = 0; ct < 4; ++ct) {
            bf16x8 bK = *(const bf16x8*)&Ks[ct * 16 + l15][g * 8];
            f32x4 z = {0.f, 0.f, 0.f, 0.f};
            s[ct] = mfma_bf16(aQ, bK, z);
        }
    }

    const float* mbase = mask + (size_t)(b & 63) * 4096;
    const float INV = 0.17677669529663688f;
    float rsum[4];
    #pragma unroll
    for (int r = 0; r < 4; ++r) {
        int row = w * 16 + g * 4 + r;
        float pr[4];
        #pragma unroll
        for (int ct = 0; ct < 4; ++ct)
            pr[ct] = (s[ct][r] + mbase[row * 64 + ct * 16 + l15]) * INV;
        float m = fmaxf(fmaxf(pr[0], pr[1]), fmaxf(pr[2], pr[3]));
        #pragma unroll
        for (int off = 1; off < 16; off <<= 1)
            m = fmaxf(m, __shfl_xor(m, off));
        float sum = 0.f;
        #pragma unroll
        for (int ct = 0; ct < 4; ++ct) { pr[ct] = __expf(pr[ct] - m); sum += pr[ct]; }
        #pragma unroll
        for (int off = 1; off < 16; off <<= 1)
            sum += __shfl_xor(sum, off);
        rsum[r] = sum;
        #pragma unroll
        for (int ct = 0; ct < 4; ++ct)
            Ps[row][ct * 16 + l15] = f2bf(pr[ct]);
    }

    f32x4 o[2] = {};
    #pragma unroll
    for (int ks = 0; ks < 2; ++ks) {
        bf16x8 pa = *(const bf16x8*)&Ps[w * 16 + l15][ks * 32 + g * 8];
        #pragma unroll
        for (int n = 0; n < 2; ++n) {
            bf16x8 vb = *(const bf16x8*)&Vt[n * 16 + l15][ks * 32 + g * 8];
            o[n] = mfma_bf16(pa, vb, o[n]);
        }
    }

    #pragma unroll
    for (int n = 0; n < 2; ++n) {
        #pragma unroll
        for (int r = 0; r < 4; ++r) {
            int row = w * 16 + g * 4 + r;
            size_t idx = ((size_t)(b * 64 + row)) * 256 + h * 32 + n * 16 + l15;
            float val = o[n][r] / rsum[r];
            if (BF16X) xo_b[idx] = f2bf(val);
            else       xo_f[idx] = val;
        }
    }
}

// ---------------------------------------------------------------------------
// Fused MLP v18 = v16 body + block-parity chunk-offset stagger: odd blocks
// start the hidden-chunk loop at 16 (wrap). The two co-resident blocks on a
// CU then sit permanently in different phases, so one block's GELU (VALU)
// overlaps the other's MFMA clusters instead of convoying. Accumulation over
// chunks is commutative -> bit-level correctness unchanged except fp add
// order within oacc (associativity-safe at our threshold).
// ---------------------------------------------------------------------------
template <bool BF16X>
__global__ __launch_bounds__(256, 2) void mlp_fused(
    const float* __restrict__ xin_f, const unsigned short* __restrict__ xin_b,
    float* __restrict__ out,
    const unsigned short* __restrict__ wt1, const float* __restrict__ b1,
    const unsigned short* __restrict__ wt2, const float* __restrict__ b2)
{
    __shared__ unsigned short w1c[2][8192];     // 16 KB per buf
    __shared__ unsigned short w2c[2][8192];
    __shared__ float b1s[1024];

    const int tid  = threadIdx.x;
    const int lane = tid & 63;
    const int l31  = lane & 31;
    const int hi   = lane >> 5;
    const int wid  = tid >> 6;                  // 0..3
    const int fb   = lane * 8;                  // frag offset within 512-short span
    const int off  = (blockIdx.x & 1) * 16;     // phase-decorrelation offset

    const size_t rowbase = (size_t)blockIdx.x * 128 + wid * 32;

    auto stage = [&](const unsigned short* gbase, unsigned short* lbase) {
        #pragma unroll
        for (int i = 0; i < 4; ++i) {
            load_lds16(gbase + (i * 256 + tid) * 8,
                       lbase + (i * 256 + wid * 64) * 8);
        }
    };

    stage(wt1 + (size_t)off * 8192, &w1c[0][0]);
    stage(wt2 + (size_t)off * 8192, &w2c[0][0]);

    b1s[tid]       = b1[tid];
    b1s[tid + 256] = b1[tid + 256];
    b1s[tid + 512] = b1[tid + 512];
    b1s[tid + 768] = b1[tid + 768];

    // x fragments: B-operand, lane = own x-row (l31), k = hi*8+e. 64 VGPR.
    bf16x8 xf[16];
    if (BF16X) {
        const unsigned short* xr = xin_b + (rowbase + l31) * 256;
        #pragma unroll
        for (int ks = 0; ks < 16; ++ks)
            xf[ks] = *(const bf16x8*)(xr + ks * 16 + hi * 8);
    } else {
        const float* xr = xin_f + (rowbase + l31) * 256;
        #pragma unroll
        for (int ks = 0; ks < 16; ++ks) {
            float4 a0 = *(const float4*)(xr + ks * 16 + hi * 8);
            float4 a1 = *(const float4*)(xr + ks * 16 + hi * 8 + 4);
            xf[ks] = pack8(a0, a1);
        }
    }

    f32x16 oacc[8] = {};   // 32 rows x 256 cols (8 col-tiles of 32)

    for (int c = 0; c < 32; ++c) {
        const int cur = c & 1;
        const int cc  = (c + off) & 31;         // actual hidden chunk
        __syncthreads();   // drains chunk DMA; frees buf cur^1 for prefetch

        if (c < 31) {
            const int cn = (c + 1 + off) & 31;
            stage(wt1 + (size_t)cn * 8192, &w1c[cur ^ 1][0]);
            stage(wt2 + (size_t)cn * 8192, &w2c[cur ^ 1][0]);
        }

        // ---- bias-seeded h accumulator ----
        f32x16 hacc;
        {
            const float* bp = &b1s[cc * 32 + hi * 8];
            float4 b0 = *(const float4*)(bp);
            float4 b1v = *(const float4*)(bp + 4);
            float4 b2v = *(const float4*)(bp + 16);
            float4 b3 = *(const float4*)(bp + 20);
            hacc[0]=b0.x;  hacc[1]=b0.y;  hacc[2]=b0.z;  hacc[3]=b0.w;
            hacc[4]=b1v.x; hacc[5]=b1v.y; hacc[6]=b1v.z; hacc[7]=b1v.w;
            hacc[8]=b2v.x; hacc[9]=b2v.y; hacc[10]=b2v.z; hacc[11]=b2v.w;
            hacc[12]=b3.x; hacc[13]=b3.y; hacc[14]=b3.z; hacc[15]=b3.w;
        }

        // ---- h-phase: 16 chained mfma32 over K=256 ----
        __builtin_amdgcn_s_setprio(1);
        #pragma unroll
        for (int ks = 0; ks < 16; ++ks) {
            bf16x8 wf = *(const bf16x8*)&w1c[cur][ks * 512 + fb];
            hacc = mfma32(wf, xf[ks], hacc);
        }
        __builtin_amdgcn_s_setprio(0);

        // ---- GELU in registers -> two out-MFMA A-frags ----
        bf16x8 aH0, aH1;
        #pragma unroll
        for (int e = 0; e < 8; ++e) {
            aH0[e] = (short)f2bf(gelu_erf(hacc[e]));
            aH1[e] = (short)f2bf(gelu_erf(hacc[e + 8]));
        }

        // ---- out-phase: 8 col-tiles x 2 K-halves ----
        __builtin_amdgcn_s_setprio(1);
        #pragma unroll
        for (int n = 0; n < 8; ++n) {
            bf16x8 bF0 = *(const bf16x8*)&w2c[cur][(n * 2 + 0) * 512 + fb];
            bf16x8 bF1 = *(const bf16x8*)&w2c[cur][(n * 2 + 1) * 512 + fb];
            oacc[n] = mfma32(aH0, bF0, oacc[n]);
            oacc[n] = mfma32(aH1, bF1, oacc[n]);
        }
        __builtin_amdgcn_s_setprio(0);
    }

    // ---- epilogue: out = oacc + b2 + residual ----
    #pragma unroll
    for (int n = 0; n < 8; ++n) {
        int col = n * 32 + l31;
        float bias = b2[col];
        #pragma unroll
        for (int r = 0; r < 16; ++r) {
            int row_local = (r & 3) + 8 * (r >> 2) + 4 * hi;
            size_t idx = (rowbase + row_local) * 256 + col;
            float resid = BF16X ? bf2f(xin_b[idx]) : xin_f[idx];
            out[idx] = oacc[n][r] + bias + resid;
        }
    }
}

// ---------------------------------------------------------------------------
extern "C" void kernel_launch(void* const* d_in, const int* in_sizes, int n_in,
                              void* d_out, int out_size, void* d_ws, size_t ws_size,
                              hipStream_t stream)
{
    const float* q    = (const float*)d_in[0];
    const float* k    = (const float*)d_in[1];
    const float* v    = (const float*)d_in[2];
    const float* mask = (const float*)d_in[3];
    const float* w1   = (const float*)d_in[6];
    const float* b1   = (const float*)d_in[7];
    const float* w2   = (const float*)d_in[8];
    const float* b2   = (const float*)d_in[9];

    float* out = (float*)d_out;

    unsigned short* wt1 = (unsigned short*)d_ws;                 // 512 KB
    unsigned short* wt2 = wt1 + (size_t)1024 * 256;              // 512 KB
    unsigned short* xbf = wt2 + (size_t)1024 * 256;              // 32 MB (bf16 x)

    const size_t need = (size_t)2 * 1024 * 256 * 2 + (size_t)65536 * 256 * 2;

    if (ws_size >= need) {
        attn_prep_kernel<true><<<8256, 256, 0, stream>>>(
            q, k, v, mask, nullptr, xbf, w1, wt1, w2, wt2);
        mlp_fused<true><<<512, 256, 0, stream>>>(
            nullptr, xbf, out, wt1, b1, wt2, b2);
    } else {
        attn_prep_kernel<false><<<8256, 256, 0, stream>>>(
            q, k, v, mask, out, nullptr, w1, wt1, w2, wt2);
        mlp_fused<false><<<512, 256, 0, stream>>>(
            out, nullptr, out, wt1, b1, wt2, b2);
    }
}